// Round 4
// baseline (366.279 us; speedup 1.0000x reference)
//
#include <hip/hip_runtime.h>
#include <stdint.h>

// Causal self-attention, B=8 T=2048 D=EMB=1024, fp32 in/out.
// Pipeline: x,W -> fp16; q/k/v proj (f16 MFMA); S=qk^T/32; E=exp(S) fp16
// (scores ~N(0,1), max ~5.5 -> no overflow; reference softmax is GLOBAL per
// batch so no max-shift); Z_b = sum(E); out = (E@v)/Z fp32.
//
// R4: (1) proj -> 128x256 tile, BK=32, 48KB LDS, acc[4][4] (64 VGPR) ->
// __launch_bounds__(512,4) = 2 blocks/CU; co-resident block hides the
// serial ds_read+MFMA phases (m97 mechanism). Derived waits: vmcnt(1) per
// tile, A staged 3 phases ahead, B 2. (2) scores -> NF=1 (256x128) jobs,
// 72/batch, grid 256, 2-3 jobs per block (kills the 32-block 2nd round).

#define B_   8
#define T_   2048
#define DIM  1024

typedef _Float16 f16;
typedef f16   f16x8 __attribute__((ext_vector_type(8)));
typedef f16   f16x4 __attribute__((ext_vector_type(4)));
typedef float f32x4 __attribute__((ext_vector_type(4)));

typedef const __attribute__((address_space(1))) void gvoid_t;
typedef __attribute__((address_space(3))) void lvoid_t;

// ================= shared staging/frag helpers =================
// 64-col layout (BK=64 cores): 16B segments XOR-swizzled by (row&7).
__device__ __forceinline__ void stage_half256(const uint16_t* __restrict__ g, int ld,
                                              uint16_t* s, int tid) {
#pragma unroll
  for (int j = 0; j < 2; ++j) {
    int r   = j * 64 + (tid >> 3);
    int seg = (tid & 7) ^ (r & 7);
    const uint16_t* gp = g + (size_t)r * ld + seg * 8;
    uint16_t* sp = s + j * 4096 + (tid >> 6) * 512;  // wave-uniform; HW adds lane*16B
    __builtin_amdgcn_global_load_lds((gvoid_t*)gp, (lvoid_t*)sp, 16, 0, 0);
  }
}

__device__ __forceinline__ f16x8 frag64(const uint16_t* s, int r, int gseg) {
  return *(const f16x8*)(s + r * 64 + ((gseg ^ (r & 7)) * 8));
}

// 32-col layout (BK=32 core): 4 segs/row, XOR by (row&3).
// One stage unit = 512 thr x 16B = 128 rows x 32 cols.
__device__ __forceinline__ void stage_u8k(const uint16_t* __restrict__ g, int ld,
                                          uint16_t* s, int tid) {
  int r   = tid >> 2;
  int seg = (tid & 3) ^ (r & 3);
  const uint16_t* gp = g + (size_t)r * ld + seg * 8;
  uint16_t* sp = s + (tid >> 6) * 512;
  __builtin_amdgcn_global_load_lds((gvoid_t*)gp, (lvoid_t*)sp, 16, 0, 0);
}

__device__ __forceinline__ f16x8 frag32(const uint16_t* s, int r, int gseg) {
  return *(const f16x8*)(s + r * 32 + ((gseg ^ (r & 3)) * 8));
}

__device__ __forceinline__ void lda4(const uint16_t* s, int rbase, int quad, int l15,
                                     f16x8 o[4][2]) {
#pragma unroll
  for (int mf = 0; mf < 4; ++mf) {
    int r = rbase + mf * 16 + l15;
#pragma unroll
    for (int kk = 0; kk < 2; ++kk) o[mf][kk] = frag64(s, r, kk * 4 + quad);
  }
}

__device__ __forceinline__ void ldb1(const uint16_t* s, int rbase, int quad, int l15,
                                     f16x8 o[2]) {
  int r = rbase + l15;
#pragma unroll
  for (int kk = 0; kk < 2; ++kk) o[kk] = frag64(s, r, kk * 4 + quad);
}

__device__ __forceinline__ void lda4q(const uint16_t* s, int rbase, int quad, int l15,
                                      f16x8 o[4]) {
#pragma unroll
  for (int mf = 0; mf < 4; ++mf) o[mf] = frag32(s, rbase + mf * 16 + l15, quad);
}

__device__ __forceinline__ void ldb2q(const uint16_t* s, int rbase, int quad, int l15,
                                      f16x8 o[2]) {
#pragma unroll
  for (int nf = 0; nf < 2; ++nf) o[nf] = frag32(s, rbase + nf * 16 + l15, quad);
}

template <int M0, int N0>
__device__ __forceinline__ void mm8(f16x8 a[4][2], f16x8 b[2], f32x4 (&acc)[8][2]) {
#pragma unroll
  for (int kk = 0; kk < 2; ++kk)
#pragma unroll
    for (int mf = 0; mf < 4; ++mf)
      acc[M0 + mf][N0] = __builtin_amdgcn_mfma_f32_16x16x32_f16(
          a[mf][kk], b[kk], acc[M0 + mf][N0], 0, 0, 0);
}

template <int N0>
__device__ __forceinline__ void mm8q(f16x8 a[4], f16x8 b[2], f32x4 (&acc)[4][4]) {
#pragma unroll
  for (int mf = 0; mf < 4; ++mf)
#pragma unroll
    for (int nf = 0; nf < 2; ++nf)
      acc[mf][N0 + nf] = __builtin_amdgcn_mfma_f32_16x16x32_f16(
          a[mf], b[nf], acc[mf][N0 + nf], 0, 0, 0);
}

#define SYNC_MFMA8(AA, BB, M0, N0)                     \
  __builtin_amdgcn_s_barrier();                        \
  asm volatile("s_waitcnt lgkmcnt(0)" ::: "memory");   \
  __builtin_amdgcn_s_setprio(1);                       \
  mm8<M0, N0>(AA, BB, acc);                            \
  __builtin_amdgcn_s_setprio(0);                       \
  __builtin_amdgcn_s_barrier();

#define SYNC_MFMA8Q(AA, BB, N0)                        \
  __builtin_amdgcn_s_barrier();                        \
  asm volatile("s_waitcnt lgkmcnt(0)" ::: "memory");   \
  __builtin_amdgcn_s_setprio(1);                       \
  mm8q<N0>(AA, BB, acc);                               \
  __builtin_amdgcn_s_setprio(0);                       \
  __builtin_amdgcn_s_barrier();

// ---- BK=32 core: acc += A(128xK) @ B(256xK)^T, K = nTiles*32, even >=4 ----
// 512 thr, 8 waves 2Mx4N, per-wave 64x64, acc[4][4]=64 VGPR, LDS 48KB
// (A 2x8KB + B 2x16KB) -> 2 blocks/CU at launch_bounds(512,4).
// Phase = {ds_reads; stage; [vmcnt]; barrier; lgkm0; 8 MFMA; barrier};
// 2 phases per tile. Stage schedule (per-wave ledger, oldest->newest):
//   entry ph1 of tile t: [A(t+1)]
//   ph1: +B(t+1)(2u) -> [A(t+1),B(t+1)]         (reads buf[t%2] A + B-lo)
//   ph2: +A(t+2)(1u); vmcnt(1) retires A(t+1),B(t+1) -> [A(t+2)]
//   ph3/ph4 mirror with buf parity flipped.
// A covered 3 phases, B 2. Tail: ph2 vmcnt(0), no dead stages.
__device__ __forceinline__ void gemm128x256_bk32(const uint16_t* __restrict__ gA,
                                                 const uint16_t* __restrict__ gB,
                                                 int lda, int ldb, int nTiles,
                                                 uint16_t* smem, f32x4 (&acc)[4][4]) {
  const int tid = threadIdx.x, lane = tid & 63;
  const int quad = lane >> 4, l15 = lane & 15;
  const int wv = tid >> 6, wr = wv >> 2, wc = wv & 3;

  uint16_t* sA0 = smem;            // 4096 u16 = 8KB
  uint16_t* sA1 = smem + 4096;
  uint16_t* sB0 = smem + 8192;     // 8192 u16 = 16KB
  uint16_t* sB1 = smem + 16384;

  // prologue: A(0) 1u, B(0) 2u, A(1) 1u; vmcnt(1) keeps A(1) in flight.
  stage_u8k(gA,                          lda, sA0,        tid);
  stage_u8k(gB,                          ldb, sB0,        tid);
  stage_u8k(gB + 128 * (size_t)ldb,      ldb, sB0 + 4096, tid);
  stage_u8k(gA + 32,                     lda, sA1,        tid);
  asm volatile("s_waitcnt vmcnt(1)" ::: "memory");
  __builtin_amdgcn_s_barrier();

  f16x8 a[4], b0[2], b1[2];
#pragma unroll 1
  for (int it = 0; it < nTiles / 2 - 1; ++it) {
    const uint16_t* gAn = gA + (2 * it + 2) * 32;   // A(t+2), A(t+3)
    const uint16_t* gBn = gB + (2 * it + 1) * 32;   // B(t+1), B(t+2)
    // ph1 (tile t, buf0): A all + B lo; stage B(t+1)->buf1.B
    lda4q(sA0, wr * 64,      quad, l15, a);
    ldb2q(sB0, wc * 64,      quad, l15, b0);
    stage_u8k(gBn,                     ldb, sB1,        tid);
    stage_u8k(gBn + 128 * (size_t)ldb, ldb, sB1 + 4096, tid);
    SYNC_MFMA8Q(a, b0, 0)
    // ph2: B hi; stage A(t+2)->buf0.A; retire A(t+1),B(t+1)
    ldb2q(sB0, wc * 64 + 32, quad, l15, b1);
    stage_u8k(gAn, lda, sA0, tid);
    asm volatile("s_waitcnt vmcnt(1)" ::: "memory");
    SYNC_MFMA8Q(a, b1, 2)
    // ph3 (tile t+1, buf1): A all + B lo; stage B(t+2)->buf0.B
    lda4q(sA1, wr * 64,      quad, l15, a);
    ldb2q(sB1, wc * 64,      quad, l15, b0);
    stage_u8k(gBn + 32,                     ldb, sB0,        tid);
    stage_u8k(gBn + 32 + 128 * (size_t)ldb, ldb, sB0 + 4096, tid);
    SYNC_MFMA8Q(a, b0, 0)
    // ph4: B hi; stage A(t+3)->buf1.A; retire A(t+2),B(t+2)
    ldb2q(sB1, wc * 64 + 32, quad, l15, b1);
    stage_u8k(gAn + 32, lda, sA1, tid);
    asm volatile("s_waitcnt vmcnt(1)" ::: "memory");
    SYNC_MFMA8Q(a, b1, 2)
  }
  // tail: tiles n-2 (buf0), n-1 (buf1); only B(n-1) stage is live.
  {
    const uint16_t* gBn = gB + (nTiles - 1) * 32;
    lda4q(sA0, wr * 64,      quad, l15, a);
    ldb2q(sB0, wc * 64,      quad, l15, b0);
    stage_u8k(gBn,                     ldb, sB1,        tid);
    stage_u8k(gBn + 128 * (size_t)ldb, ldb, sB1 + 4096, tid);
    SYNC_MFMA8Q(a, b0, 0)
    ldb2q(sB0, wc * 64 + 32, quad, l15, b1);
    asm volatile("s_waitcnt vmcnt(0)" ::: "memory");
    SYNC_MFMA8Q(a, b1, 2)
    lda4q(sA1, wr * 64,      quad, l15, a);
    ldb2q(sB1, wc * 64,      quad, l15, b0);
    SYNC_MFMA8Q(a, b0, 0)
    ldb2q(sB1, wc * 64 + 32, quad, l15, b1);
    SYNC_MFMA8Q(a, b1, 2)
  }
}

// ---- NF=1 BK=64 core (proven in pv): acc += A(256xK) @ B(128xK)^T ----
__device__ __forceinline__ void gemm256n128_8ph(const uint16_t* __restrict__ gA,
                                                const uint16_t* __restrict__ gB,
                                                int lda, int ldb, int nIter,
                                                uint16_t* smem, f32x4 (&acc)[8][2]) {
  const int tid = threadIdx.x, lane = tid & 63;
  const int quad = lane >> 4, l15 = lane & 15;
  const int wv = tid >> 6, wr = wv >> 2, wc = wv & 3;

  uint16_t* sA0 = smem;
  uint16_t* sA1 = smem + 16384;
  uint16_t* sB0 = smem + 32768;
  uint16_t* sB1 = smem + 40960;

  stage_half256(gA,                     lda, sA0,        tid);
  stage_half256(gA + 128 * (size_t)lda, lda, sA0 + 8192, tid);
  stage_half256(gB,                     ldb, sB0,        tid);
  stage_half256(gB + 64,                ldb, sB1,        tid);
  asm volatile("s_waitcnt vmcnt(2)" ::: "memory");
  __builtin_amdgcn_s_barrier();

  f16x8 alo[4][2], ahi[4][2], b0[2], b1[2];
#pragma unroll 1
  for (int it = 0; it < nIter - 1; ++it) {
    const int t1 = 2 * it + 1, t2 = 2 * it + 2, t3 = 2 * it + 3;
    const uint16_t* gA1 = gA + t1 * 64;
    const uint16_t* gA2 = gA + t2 * 64;

    lda4(sA0, wr * 128,      quad, l15, alo);
    ldb1(sB0, wc * 32,       quad, l15, b0);
    stage_half256(gA1, lda, sA1, tid);
    SYNC_MFMA8(alo, b0, 0, 0)
    ldb1(sB0, wc * 32 + 16,  quad, l15, b1);
    stage_half256(gA1 + 128 * (size_t)lda, lda, sA1 + 8192, tid);
    SYNC_MFMA8(alo, b1, 0, 1)
    lda4(sA0, wr * 128 + 64, quad, l15, ahi);
    stage_half256(gB + t2 * 64, ldb, sB0, tid);
    SYNC_MFMA8(ahi, b1, 4, 1)
    asm volatile("s_waitcnt vmcnt(2)" ::: "memory");
    SYNC_MFMA8(ahi, b0, 4, 0)
    lda4(sA1, wr * 128,      quad, l15, alo);
    ldb1(sB1, wc * 32,       quad, l15, b0);
    stage_half256(gA2, lda, sA0, tid);
    SYNC_MFMA8(alo, b0, 0, 0)
    ldb1(sB1, wc * 32 + 16,  quad, l15, b1);
    stage_half256(gA2 + 128 * (size_t)lda, lda, sA0 + 8192, tid);
    SYNC_MFMA8(alo, b1, 0, 1)
    lda4(sA1, wr * 128 + 64, quad, l15, ahi);
    stage_half256(gB + t3 * 64, ldb, sB1, tid);
    SYNC_MFMA8(ahi, b1, 4, 1)
    asm volatile("s_waitcnt vmcnt(2)" ::: "memory");
    SYNC_MFMA8(ahi, b0, 4, 0)
  }
  {
    const uint16_t* gA1 = gA + (2 * nIter - 1) * 64;
    lda4(sA0, wr * 128,      quad, l15, alo);
    ldb1(sB0, wc * 32,       quad, l15, b0);
    stage_half256(gA1, lda, sA1, tid);
    SYNC_MFMA8(alo, b0, 0, 0)
    ldb1(sB0, wc * 32 + 16,  quad, l15, b1);
    stage_half256(gA1 + 128 * (size_t)lda, lda, sA1 + 8192, tid);
    SYNC_MFMA8(alo, b1, 0, 1)
    lda4(sA0, wr * 128 + 64, quad, l15, ahi);
    SYNC_MFMA8(ahi, b1, 4, 1)
    asm volatile("s_waitcnt vmcnt(0)" ::: "memory");
    SYNC_MFMA8(ahi, b0, 4, 0)
    lda4(sA1, wr * 128,      quad, l15, alo);
    ldb1(sB1, wc * 32,       quad, l15, b0);
    SYNC_MFMA8(alo, b0, 0, 0)
    ldb1(sB1, wc * 32 + 16,  quad, l15, b1);
    SYNC_MFMA8(alo, b1, 0, 1)
    lda4(sA1, wr * 128 + 64, quad, l15, ahi);
    SYNC_MFMA8(ahi, b1, 4, 1)
    SYNC_MFMA8(ahi, b0, 4, 0)
  }
}

// ---------------- helpers ----------------

__global__ void zero_lrow_kernel(float* __restrict__ lrow) {
  lrow[blockIdx.x * 256 + threadIdx.x] = 0.f;
}

__global__ void conv_x_kernel(const float* __restrict__ x, f16* __restrict__ xf) {
  size_t i = (size_t)blockIdx.x * 256 + threadIdx.x;
  float4 v = ((const float4*)x)[i];
  f16x4 o = {(f16)v.x, (f16)v.y, (f16)v.z, (f16)v.w};
  ((f16x4*)xf)[i] = o;
}

// W [K][N] fp32 -> WT fp16 [z][N][K]
__global__ void convT_w_kernel(const float* __restrict__ Wq, const float* __restrict__ Wk,
                               const float* __restrict__ Wv, f16* __restrict__ WT) {
  __shared__ float tile[64][65];
  const int z = blockIdx.z;
  const float* W = (z == 0) ? Wq : (z == 1) ? Wk : Wv;
  const int r0 = blockIdx.x * 64, c0 = blockIdx.y * 64, tid = threadIdx.x;
#pragma unroll
  for (int i = 0; i < 16; ++i) {
    int rr = (tid >> 6) + 4 * i, cc = tid & 63;
    tile[rr][cc] = W[(size_t)(r0 + rr) * DIM + c0 + cc];
  }
  __syncthreads();
#pragma unroll
  for (int i = 0; i < 16; ++i) {
    int nn = (tid >> 6) + 4 * i, kk = tid & 63;
    WT[(size_t)z * DIM * DIM + (size_t)(c0 + nn) * DIM + r0 + kk] = (f16)tile[kk][nn];
  }
}

__global__ void reduce_z_kernel(const float* __restrict__ lrow, float* __restrict__ invZ) {
  const int b = blockIdx.x, tid = threadIdx.x;
  float s = 0.f;
  for (int i = tid; i < T_; i += 256) s += lrow[(size_t)b * T_ + i];
#pragma unroll
  for (int off = 1; off < 64; off <<= 1) s += __shfl_xor(s, off, 64);
  __shared__ float red[4];
  if ((tid & 63) == 0) red[tid >> 6] = s;
  __syncthreads();
  if (tid == 0) invZ[b] = 1.0f / (red[0] + red[1] + red[2] + red[3]);
}

// ---------------- main kernels ----------------

// [16384,1024] x [1024,1024]^T + bias, 128x256 tiles, BK=32, 2 blocks/CU.
// Grid 1536 = 8 XCD x 16 A-panels x 12 (z,by): A panel (256KB) L2-resident
// per XCD while the 12 (z,by) jobs cycle over it.
__global__ __launch_bounds__(512, 4) void proj_kernel(
    const f16* __restrict__ xf, const f16* __restrict__ WT,
    const float* __restrict__ bq, const float* __restrict__ bk, const float* __restrict__ bv,
    f16* __restrict__ q, f16* __restrict__ k, f16* __restrict__ vT) {
  __shared__ uint16_t smem[24576];  // 48 KB

  const int bid = blockIdx.x;
  const int xcd = bid & 7, local = bid >> 3;     // local in [0,192)
  const int bxl = local / 12, zy = local % 12;
  const int bx = xcd * 16 + bxl;                 // [0,128)
  const int z = zy >> 2, by = zy & 3;
  const size_t arow = (size_t)bx * 128;
  const int    bcol = by * 256;

  f32x4 acc[4][4];
  {
    f32x4 zz = {0.f, 0.f, 0.f, 0.f};
#pragma unroll
    for (int i = 0; i < 4; ++i)
#pragma unroll
      for (int j = 0; j < 4; ++j) acc[i][j] = zz;
  }
  gemm128x256_bk32((const uint16_t*)xf + arow * DIM,
                   (const uint16_t*)WT + (size_t)z * DIM * DIM + (size_t)bcol * DIM,
                   DIM, DIM, 32, smem, acc);

  const float* bias = (z == 0) ? bq : (z == 1) ? bk : bv;
  const int tid = threadIdx.x, lane = tid & 63, wv = tid >> 6;
  const int quad = lane >> 4, l15 = lane & 15;
  const int wr = wv >> 2, wc = wv & 3;
  if (z < 2) {
    f16* O = z ? k : q;
#pragma unroll
    for (int mf = 0; mf < 4; ++mf)
#pragma unroll
      for (int nf = 0; nf < 4; ++nf) {
        int n = bcol + wc * 64 + nf * 16 + l15;
        float bb = bias[n];
        size_t row0 = arow + wr * 64 + mf * 16 + quad * 4;
#pragma unroll
        for (int r = 0; r < 4; ++r)
          O[(row0 + r) * DIM + n] = (f16)(acc[mf][nf][r] + bb);
      }
  } else {
#pragma unroll
    for (int mf = 0; mf < 4; ++mf)
#pragma unroll
      for (int nf = 0; nf < 4; ++nf) {
        int n = bcol + wc * 64 + nf * 16 + l15;
        float bb = bias[n];
        int row0 = (int)arow + wr * 64 + mf * 16 + quad * 4;  // 4-aligned, no batch straddle
        int bb_i = row0 >> 11, t0 = row0 & 2047;
        f16x4 pk;
#pragma unroll
        for (int r = 0; r < 4; ++r) pk[r] = (f16)(acc[mf][nf][r] + bb);
        *(f16x4*)(vT + ((size_t)bb_i * DIM + n) * T_ + t0) = pk;
      }
  }
}

// E = exp((q k^T)/32) with causal mask, fp16; per-row sums -> lrow (fp32
// atomics). NF=1 jobs: 256-row stripe qi, 128-col half h in [0,2qi+2);
// 72 jobs/batch, grid 256 (32 blocks/batch, XCD b == batch b), 2-3 jobs each.
__global__ __launch_bounds__(512, 2) void scores_kernel(
    const f16* __restrict__ q, const f16* __restrict__ k,
    f16* __restrict__ E, float* __restrict__ lrow) {
  __shared__ uint16_t smem[49152];
  const int bid = blockIdx.x;
  const int b = bid & 7, blk = bid >> 3;         // blk in [0,32)

  const int tid = threadIdx.x, lane = tid & 63, wv = tid >> 6;
  const int quad = lane >> 4, l15 = lane & 15;
  const int wr = wv >> 2, wc = wv & 3;
  f16*   Eb = E + (size_t)b * T_ * T_;
  float* lb = lrow + (size_t)b * T_;

#pragma unroll 1
  for (int jid = blk; jid < 72; jid += 32) {
    int qi = 0;
    while ((qi + 1) * (qi + 2) <= jid) ++qi;     // qi(qi+1) <= jid
    const int h = jid - qi * (qi + 1);           // h in [0, 2qi+2)

    f32x4 acc[8][2];
    {
      f32x4 zz = {0.f, 0.f, 0.f, 0.f};
#pragma unroll
      for (int i = 0; i < 8; ++i) { acc[i][0] = zz; acc[i][1] = zz; }
    }
    gemm256n128_8ph((const uint16_t*)(q + ((size_t)b * T_ + qi * 256) * DIM),
                    (const uint16_t*)(k + ((size_t)b * T_ + h * 128) * DIM),
                    DIM, DIM, 8, smem, acc);

    const bool diag = (h >= 2 * qi);             // tile crosses the diagonal
#pragma unroll
    for (int mf = 0; mf < 8; ++mf) {
      float rs[4] = {0.f, 0.f, 0.f, 0.f};
#pragma unroll
      for (int nf = 0; nf < 2; ++nf)
#pragma unroll
        for (int r = 0; r < 4; ++r) {
          int t = qi * 256 + wr * 128 + mf * 16 + quad * 4 + r;
          int s = h * 128 + wc * 32 + nf * 16 + l15;
          float e = 0.f;
          if (!diag || s <= t) e = __expf(fminf(acc[mf][nf][r] * 0.03125f, 11.f));
          Eb[(size_t)t * T_ + s] = (f16)e;
          rs[r] += e;
        }
#pragma unroll
      for (int off = 1; off < 16; off <<= 1)
#pragma unroll
        for (int r = 0; r < 4; ++r) rs[r] += __shfl_xor(rs[r], off, 64);
      if (l15 == 0)
#pragma unroll
        for (int r = 0; r < 4; ++r)
          atomicAdd(&lb[qi * 256 + wr * 128 + mf * 16 + quad * 4 + r], rs[r]);
    }
  }
}

// out = (E @ v) * invZ, fp32. 256 wgs, XCD b == batch b. Block = (b, nt128,
// pair): qi=pair AND qi=7-pair -> uniform 18 half-width iterations.
__global__ __launch_bounds__(512, 2) void pv_kernel(
    const f16* __restrict__ E, const f16* __restrict__ vT,
    const float* __restrict__ invZ, float* __restrict__ out) {
  __shared__ uint16_t smem[49152];               // 96 KB
  const int bid = blockIdx.x;
  const int b = bid & 7, local = bid >> 3;       // local in [0,32)
  const int nt = local & 7, pair = local >> 3;   // nt: 128-col tile, pair in [0,4)

  const float iz = invZ[b];
  const int tid = threadIdx.x, lane = tid & 63, wv = tid >> 6;
  const int quad = lane >> 4, l15 = lane & 15;
  const int wr = wv >> 2, wc = wv & 3;
  float* ob = out + (size_t)b * T_ * DIM;
  const uint16_t* Bv = (const uint16_t*)(vT + ((size_t)b * DIM + nt * 128) * (size_t)T_);

#pragma unroll 1
  for (int j = 0; j < 2; ++j) {
    const int qi = j ? (7 - pair) : pair;
    f32x4 acc[8][2];
    {
      f32x4 z = {0.f, 0.f, 0.f, 0.f};
#pragma unroll
      for (int i = 0; i < 8; ++i) { acc[i][0] = z; acc[i][1] = z; }
    }
    gemm256n128_8ph((const uint16_t*)(E + ((size_t)b * T_ + qi * 256) * (size_t)T_),
                    Bv, T_, T_, (qi + 1) * 2, smem, acc);
#pragma unroll
    for (int mf = 0; mf < 8; ++mf)
#pragma unroll
      for (int nf = 0; nf < 2; ++nf)
#pragma unroll
        for (int r = 0; r < 4; ++r) {
          int t = qi * 256 + wr * 128 + mf * 16 + quad * 4 + r;
          int n = nt * 128 + wc * 32 + nf * 16 + l15;
          ob[(size_t)t * DIM + n] = acc[mf][nf][r] * iz;
        }
  }
}

// ---------------- launch ----------------

extern "C" void kernel_launch(void* const* d_in, const int* in_sizes, int n_in,
                              void* d_out, int out_size, void* d_ws, size_t ws_size,
                              hipStream_t stream) {
  const float* x  = (const float*)d_in[0];
  const float* Wq = (const float*)d_in[1];
  const float* bq = (const float*)d_in[2];
  const float* Wk = (const float*)d_in[3];
  const float* bk = (const float*)d_in[4];
  const float* Wv = (const float*)d_in[5];
  const float* bv = (const float*)d_in[6];
  float* out = (float*)d_out;

  char* ws = (char*)d_ws;
  // layout (bytes):
  f16*   E    = (f16*)ws;                     //  0 .. 67,108,864 (B*T*T fp16)
  f16*   xf   = (f16*)ws;                     //  alias: xf lives in E[0..SZ), dead before scores
  f16*   q    = (f16*)(ws + 67108864);        //  33,554,432
  f16*   k    = (f16*)(ws + 100663296);       //  33,554,432
  f16*   vT   = (f16*)(ws + 134217728);       //  33,554,432
  f16*   WT   = (f16*)(ws + 167772160);       //  6,291,456
  float* lrow = (float*)(ws + 174063616);     //  65,536
  float* invZ = (float*)(ws + 174129152);     //  32
  if (ws_size < (size_t)174129184) return;    // fail cleanly, not with a GPU fault

  zero_lrow_kernel<<<64, 256, 0, stream>>>(lrow);
  conv_x_kernel<<<16384, 256, 0, stream>>>(x, xf);
  convT_w_kernel<<<dim3(16, 16, 3), 256, 0, stream>>>(Wq, Wk, Wv, WT);
  proj_kernel<<<dim3(1536), 512, 0, stream>>>(xf, WT, bq, bk, bv, q, k, vT);
  scores_kernel<<<dim3(256), 512, 0, stream>>>(q, k, E, lrow);
  reduce_z_kernel<<<B_, 256, 0, stream>>>(lrow, invZ);
  pv_kernel<<<dim3(256), 512, 0, stream>>>(E, vT, invZ, out);
}

// Round 5
// 362.066 us; speedup vs baseline: 1.0116x; 1.0116x over previous
//
#include <hip/hip_runtime.h>
#include <stdint.h>

// Causal self-attention, B=8 T=2048 D=EMB=1024, fp32 in/out.
// Pipeline: x,W -> fp16; q/k/v proj (f16 MFMA); S=qk^T/32; E=exp(S) fp16
// (scores ~N(0,1), max ~5.5 -> no overflow; reference softmax is GLOBAL per
// batch so no max-shift); Z_b = sum(E); out = (E@v)/Z fp32.
//
// R5: (1) BK=32 core bank-conflict fix: seg XOR factor (r&3) -> ((r>>1)&3).
// Old form mapped 16 lanes onto 4 bank-groups (4-way conflict, 1.26e7/disp
// in R4); new form walks all 8 groups (2 lanes/group = free, m136).
// (2) scores ported to the fixed BK=32 core: uniform 128x256 jobs (K=1024),
// 72/batch, grid 576, 2 blocks/CU. pv unchanged (validate one port at a time).

#define B_   8
#define T_   2048
#define DIM  1024

typedef _Float16 f16;
typedef f16   f16x8 __attribute__((ext_vector_type(8)));
typedef f16   f16x4 __attribute__((ext_vector_type(4)));
typedef float f32x4 __attribute__((ext_vector_type(4)));

typedef const __attribute__((address_space(1))) void gvoid_t;
typedef __attribute__((address_space(3))) void lvoid_t;

// ================= staging/frag helpers =================
// 64-col layout (BK=64 core): 16B segments XOR-swizzled by (row&7).
__device__ __forceinline__ void stage_half256(const uint16_t* __restrict__ g, int ld,
                                              uint16_t* s, int tid) {
#pragma unroll
  for (int j = 0; j < 2; ++j) {
    int r   = j * 64 + (tid >> 3);
    int seg = (tid & 7) ^ (r & 7);
    const uint16_t* gp = g + (size_t)r * ld + seg * 8;
    uint16_t* sp = s + j * 4096 + (tid >> 6) * 512;  // wave-uniform; HW adds lane*16B
    __builtin_amdgcn_global_load_lds((gvoid_t*)gp, (lvoid_t*)sp, 16, 0, 0);
  }
}

__device__ __forceinline__ f16x8 frag64(const uint16_t* s, int r, int gseg) {
  return *(const f16x8*)(s + r * 64 + ((gseg ^ (r & 7)) * 8));
}

// 32-col layout (BK=32 core): 4 segs/row. XOR by ((r>>1)&3): byte group =
// (4r + seg') mod 8 then covers all 8 bank-groups over any 8 consecutive
// rows -> 2 lanes/group on ds_read_b128 (conflict-free). [R5 fix]
__device__ __forceinline__ void stage_u8k(const uint16_t* __restrict__ g, int ld,
                                          uint16_t* s, int tid) {
  int r   = tid >> 2;
  int seg = (tid & 3) ^ ((r >> 1) & 3);
  const uint16_t* gp = g + (size_t)r * ld + seg * 8;
  uint16_t* sp = s + (tid >> 6) * 512;
  __builtin_amdgcn_global_load_lds((gvoid_t*)gp, (lvoid_t*)sp, 16, 0, 0);
}

__device__ __forceinline__ f16x8 frag32(const uint16_t* s, int r, int gseg) {
  return *(const f16x8*)(s + r * 32 + ((gseg ^ ((r >> 1) & 3)) * 8));
}

__device__ __forceinline__ void lda4(const uint16_t* s, int rbase, int quad, int l15,
                                     f16x8 o[4][2]) {
#pragma unroll
  for (int mf = 0; mf < 4; ++mf) {
    int r = rbase + mf * 16 + l15;
#pragma unroll
    for (int kk = 0; kk < 2; ++kk) o[mf][kk] = frag64(s, r, kk * 4 + quad);
  }
}

__device__ __forceinline__ void ldb1(const uint16_t* s, int rbase, int quad, int l15,
                                     f16x8 o[2]) {
  int r = rbase + l15;
#pragma unroll
  for (int kk = 0; kk < 2; ++kk) o[kk] = frag64(s, r, kk * 4 + quad);
}

__device__ __forceinline__ void lda4q(const uint16_t* s, int rbase, int quad, int l15,
                                      f16x8 o[4]) {
#pragma unroll
  for (int mf = 0; mf < 4; ++mf) o[mf] = frag32(s, rbase + mf * 16 + l15, quad);
}

__device__ __forceinline__ void ldb2q(const uint16_t* s, int rbase, int quad, int l15,
                                      f16x8 o[2]) {
#pragma unroll
  for (int nf = 0; nf < 2; ++nf) o[nf] = frag32(s, rbase + nf * 16 + l15, quad);
}

template <int M0, int N0>
__device__ __forceinline__ void mm8(f16x8 a[4][2], f16x8 b[2], f32x4 (&acc)[8][2]) {
#pragma unroll
  for (int kk = 0; kk < 2; ++kk)
#pragma unroll
    for (int mf = 0; mf < 4; ++mf)
      acc[M0 + mf][N0] = __builtin_amdgcn_mfma_f32_16x16x32_f16(
          a[mf][kk], b[kk], acc[M0 + mf][N0], 0, 0, 0);
}

template <int N0>
__device__ __forceinline__ void mm8q(f16x8 a[4], f16x8 b[2], f32x4 (&acc)[4][4]) {
#pragma unroll
  for (int mf = 0; mf < 4; ++mf)
#pragma unroll
    for (int nf = 0; nf < 2; ++nf)
      acc[mf][N0 + nf] = __builtin_amdgcn_mfma_f32_16x16x32_f16(
          a[mf], b[nf], acc[mf][N0 + nf], 0, 0, 0);
}

#define SYNC_MFMA8(AA, BB, M0, N0)                     \
  __builtin_amdgcn_s_barrier();                        \
  asm volatile("s_waitcnt lgkmcnt(0)" ::: "memory");   \
  __builtin_amdgcn_s_setprio(1);                       \
  mm8<M0, N0>(AA, BB, acc);                            \
  __builtin_amdgcn_s_setprio(0);                       \
  __builtin_amdgcn_s_barrier();

#define SYNC_MFMA8Q(AA, BB, N0)                        \
  __builtin_amdgcn_s_barrier();                        \
  asm volatile("s_waitcnt lgkmcnt(0)" ::: "memory");   \
  __builtin_amdgcn_s_setprio(1);                       \
  mm8q<N0>(AA, BB, acc);                               \
  __builtin_amdgcn_s_setprio(0);                       \
  __builtin_amdgcn_s_barrier();

// ---- BK=32 core: acc += A(128xK) @ B(256xK)^T, K = nTiles*32, even >=4 ----
// 512 thr, 8 waves 2Mx4N, per-wave 64x64, acc[4][4]=64 VGPR, LDS 48KB
// (A 2x8KB + B 2x16KB) -> 2 blocks/CU at launch_bounds(512,4).
// Stage ledger (oldest->newest): entry ph1 of tile t: [A(t+1)];
// ph1 +B(t+1); ph2 +A(t+2), vmcnt(1) retires A(t+1),B(t+1); mirror ph3/4.
__device__ __forceinline__ void gemm128x256_bk32(const uint16_t* __restrict__ gA,
                                                 const uint16_t* __restrict__ gB,
                                                 int lda, int ldb, int nTiles,
                                                 uint16_t* smem, f32x4 (&acc)[4][4]) {
  const int tid = threadIdx.x, lane = tid & 63;
  const int quad = lane >> 4, l15 = lane & 15;
  const int wv = tid >> 6, wr = wv >> 2, wc = wv & 3;

  uint16_t* sA0 = smem;            // 4096 u16 = 8KB
  uint16_t* sA1 = smem + 4096;
  uint16_t* sB0 = smem + 8192;     // 8192 u16 = 16KB
  uint16_t* sB1 = smem + 16384;

  stage_u8k(gA,                          lda, sA0,        tid);
  stage_u8k(gB,                          ldb, sB0,        tid);
  stage_u8k(gB + 128 * (size_t)ldb,      ldb, sB0 + 4096, tid);
  stage_u8k(gA + 32,                     lda, sA1,        tid);
  asm volatile("s_waitcnt vmcnt(1)" ::: "memory");
  __builtin_amdgcn_s_barrier();

  f16x8 a[4], b0[2], b1[2];
#pragma unroll 1
  for (int it = 0; it < nTiles / 2 - 1; ++it) {
    const uint16_t* gAn = gA + (2 * it + 2) * 32;   // A(t+2), A(t+3)
    const uint16_t* gBn = gB + (2 * it + 1) * 32;   // B(t+1), B(t+2)
    // ph1 (tile t, buf0): A all + B lo; stage B(t+1)->buf1.B
    lda4q(sA0, wr * 64,      quad, l15, a);
    ldb2q(sB0, wc * 64,      quad, l15, b0);
    stage_u8k(gBn,                     ldb, sB1,        tid);
    stage_u8k(gBn + 128 * (size_t)ldb, ldb, sB1 + 4096, tid);
    SYNC_MFMA8Q(a, b0, 0)
    // ph2: B hi; stage A(t+2)->buf0.A; retire A(t+1),B(t+1)
    ldb2q(sB0, wc * 64 + 32, quad, l15, b1);
    stage_u8k(gAn, lda, sA0, tid);
    asm volatile("s_waitcnt vmcnt(1)" ::: "memory");
    SYNC_MFMA8Q(a, b1, 2)
    // ph3 (tile t+1, buf1): A all + B lo; stage B(t+2)->buf0.B
    lda4q(sA1, wr * 64,      quad, l15, a);
    ldb2q(sB1, wc * 64,      quad, l15, b0);
    stage_u8k(gBn + 32,                     ldb, sB0,        tid);
    stage_u8k(gBn + 32 + 128 * (size_t)ldb, ldb, sB0 + 4096, tid);
    SYNC_MFMA8Q(a, b0, 0)
    // ph4: B hi; stage A(t+3)->buf1.A; retire A(t+2),B(t+2)
    ldb2q(sB1, wc * 64 + 32, quad, l15, b1);
    stage_u8k(gAn + 32, lda, sA1, tid);
    asm volatile("s_waitcnt vmcnt(1)" ::: "memory");
    SYNC_MFMA8Q(a, b1, 2)
  }
  // tail: tiles n-2 (buf0), n-1 (buf1); only B(n-1) stage is live.
  {
    const uint16_t* gBn = gB + (nTiles - 1) * 32;
    lda4q(sA0, wr * 64,      quad, l15, a);
    ldb2q(sB0, wc * 64,      quad, l15, b0);
    stage_u8k(gBn,                     ldb, sB1,        tid);
    stage_u8k(gBn + 128 * (size_t)ldb, ldb, sB1 + 4096, tid);
    SYNC_MFMA8Q(a, b0, 0)
    ldb2q(sB0, wc * 64 + 32, quad, l15, b1);
    asm volatile("s_waitcnt vmcnt(0)" ::: "memory");
    SYNC_MFMA8Q(a, b1, 2)
    lda4q(sA1, wr * 64,      quad, l15, a);
    ldb2q(sB1, wc * 64,      quad, l15, b0);
    SYNC_MFMA8Q(a, b0, 0)
    ldb2q(sB1, wc * 64 + 32, quad, l15, b1);
    SYNC_MFMA8Q(a, b1, 2)
  }
}

// ---- NF=1 BK=64 core (pv): acc += A(256xK) @ B(128xK)^T ----
__device__ __forceinline__ void gemm256n128_8ph(const uint16_t* __restrict__ gA,
                                                const uint16_t* __restrict__ gB,
                                                int lda, int ldb, int nIter,
                                                uint16_t* smem, f32x4 (&acc)[8][2]) {
  const int tid = threadIdx.x, lane = tid & 63;
  const int quad = lane >> 4, l15 = lane & 15;
  const int wv = tid >> 6, wr = wv >> 2, wc = wv & 3;

  uint16_t* sA0 = smem;
  uint16_t* sA1 = smem + 16384;
  uint16_t* sB0 = smem + 32768;
  uint16_t* sB1 = smem + 40960;

  stage_half256(gA,                     lda, sA0,        tid);
  stage_half256(gA + 128 * (size_t)lda, lda, sA0 + 8192, tid);
  stage_half256(gB,                     ldb, sB0,        tid);
  stage_half256(gB + 64,                ldb, sB1,        tid);
  asm volatile("s_waitcnt vmcnt(2)" ::: "memory");
  __builtin_amdgcn_s_barrier();

  f16x8 alo[4][2], ahi[4][2], b0[2], b1[2];
#pragma unroll 1
  for (int it = 0; it < nIter - 1; ++it) {
    const int t1 = 2 * it + 1, t2 = 2 * it + 2, t3 = 2 * it + 3;
    const uint16_t* gA1 = gA + t1 * 64;
    const uint16_t* gA2 = gA + t2 * 64;

    lda4(sA0, wr * 128,      quad, l15, alo);
    ldb1(sB0, wc * 32,       quad, l15, b0);
    stage_half256(gA1, lda, sA1, tid);
    SYNC_MFMA8(alo, b0, 0, 0)
    ldb1(sB0, wc * 32 + 16,  quad, l15, b1);
    stage_half256(gA1 + 128 * (size_t)lda, lda, sA1 + 8192, tid);
    SYNC_MFMA8(alo, b1, 0, 1)
    lda4(sA0, wr * 128 + 64, quad, l15, ahi);
    stage_half256(gB + t2 * 64, ldb, sB0, tid);
    SYNC_MFMA8(ahi, b1, 4, 1)
    asm volatile("s_waitcnt vmcnt(2)" ::: "memory");
    SYNC_MFMA8(ahi, b0, 4, 0)
    lda4(sA1, wr * 128,      quad, l15, alo);
    ldb1(sB1, wc * 32,       quad, l15, b0);
    stage_half256(gA2, lda, sA0, tid);
    SYNC_MFMA8(alo, b0, 0, 0)
    ldb1(sB1, wc * 32 + 16,  quad, l15, b1);
    stage_half256(gA2 + 128 * (size_t)lda, lda, sA0 + 8192, tid);
    SYNC_MFMA8(alo, b1, 0, 1)
    lda4(sA1, wr * 128 + 64, quad, l15, ahi);
    stage_half256(gB + t3 * 64, ldb, sB1, tid);
    SYNC_MFMA8(ahi, b1, 4, 1)
    asm volatile("s_waitcnt vmcnt(2)" ::: "memory");
    SYNC_MFMA8(ahi, b0, 4, 0)
  }
  {
    const uint16_t* gA1 = gA + (2 * nIter - 1) * 64;
    lda4(sA0, wr * 128,      quad, l15, alo);
    ldb1(sB0, wc * 32,       quad, l15, b0);
    stage_half256(gA1, lda, sA1, tid);
    SYNC_MFMA8(alo, b0, 0, 0)
    ldb1(sB0, wc * 32 + 16,  quad, l15, b1);
    stage_half256(gA1 + 128 * (size_t)lda, lda, sA1 + 8192, tid);
    SYNC_MFMA8(alo, b1, 0, 1)
    lda4(sA0, wr * 128 + 64, quad, l15, ahi);
    SYNC_MFMA8(ahi, b1, 4, 1)
    asm volatile("s_waitcnt vmcnt(0)" ::: "memory");
    SYNC_MFMA8(ahi, b0, 4, 0)
    lda4(sA1, wr * 128,      quad, l15, alo);
    ldb1(sB1, wc * 32,       quad, l15, b0);
    SYNC_MFMA8(alo, b0, 0, 0)
    ldb1(sB1, wc * 32 + 16,  quad, l15, b1);
    SYNC_MFMA8(alo, b1, 0, 1)
    lda4(sA1, wr * 128 + 64, quad, l15, ahi);
    SYNC_MFMA8(ahi, b1, 4, 1)
    SYNC_MFMA8(ahi, b0, 4, 0)
  }
}

// ---------------- helpers ----------------

__global__ void zero_lrow_kernel(float* __restrict__ lrow) {
  lrow[blockIdx.x * 256 + threadIdx.x] = 0.f;
}

__global__ void conv_x_kernel(const float* __restrict__ x, f16* __restrict__ xf) {
  size_t i = (size_t)blockIdx.x * 256 + threadIdx.x;
  float4 v = ((const float4*)x)[i];
  f16x4 o = {(f16)v.x, (f16)v.y, (f16)v.z, (f16)v.w};
  ((f16x4*)xf)[i] = o;
}

// W [K][N] fp32 -> WT fp16 [z][N][K]
__global__ void convT_w_kernel(const float* __restrict__ Wq, const float* __restrict__ Wk,
                               const float* __restrict__ Wv, f16* __restrict__ WT) {
  __shared__ float tile[64][65];
  const int z = blockIdx.z;
  const float* W = (z == 0) ? Wq : (z == 1) ? Wk : Wv;
  const int r0 = blockIdx.x * 64, c0 = blockIdx.y * 64, tid = threadIdx.x;
#pragma unroll
  for (int i = 0; i < 16; ++i) {
    int rr = (tid >> 6) + 4 * i, cc = tid & 63;
    tile[rr][cc] = W[(size_t)(r0 + rr) * DIM + c0 + cc];
  }
  __syncthreads();
#pragma unroll
  for (int i = 0; i < 16; ++i) {
    int nn = (tid >> 6) + 4 * i, kk = tid & 63;
    WT[(size_t)z * DIM * DIM + (size_t)(c0 + nn) * DIM + r0 + kk] = (f16)tile[kk][nn];
  }
}

__global__ void reduce_z_kernel(const float* __restrict__ lrow, float* __restrict__ invZ) {
  const int b = blockIdx.x, tid = threadIdx.x;
  float s = 0.f;
  for (int i = tid; i < T_; i += 256) s += lrow[(size_t)b * T_ + i];
#pragma unroll
  for (int off = 1; off < 64; off <<= 1) s += __shfl_xor(s, off, 64);
  __shared__ float red[4];
  if ((tid & 63) == 0) red[tid >> 6] = s;
  __syncthreads();
  if (tid == 0) invZ[b] = 1.0f / (red[0] + red[1] + red[2] + red[3]);
}

// ---------------- main kernels ----------------

// [16384,1024] x [1024,1024]^T + bias, 128x256 tiles, BK=32, 2 blocks/CU.
__global__ __launch_bounds__(512, 4) void proj_kernel(
    const f16* __restrict__ xf, const f16* __restrict__ WT,
    const float* __restrict__ bq, const float* __restrict__ bk, const float* __restrict__ bv,
    f16* __restrict__ q, f16* __restrict__ k, f16* __restrict__ vT) {
  __shared__ uint16_t smem[24576];  // 48 KB

  const int bid = blockIdx.x;
  const int xcd = bid & 7, local = bid >> 3;     // local in [0,192)
  const int bxl = local / 12, zy = local % 12;
  const int bx = xcd * 16 + bxl;                 // [0,128)
  const int z = zy >> 2, by = zy & 3;
  const size_t arow = (size_t)bx * 128;
  const int    bcol = by * 256;

  f32x4 acc[4][4];
  {
    f32x4 zz = {0.f, 0.f, 0.f, 0.f};
#pragma unroll
    for (int i = 0; i < 4; ++i)
#pragma unroll
      for (int j = 0; j < 4; ++j) acc[i][j] = zz;
  }
  gemm128x256_bk32((const uint16_t*)xf + arow * DIM,
                   (const uint16_t*)WT + (size_t)z * DIM * DIM + (size_t)bcol * DIM,
                   DIM, DIM, 32, smem, acc);

  const float* bias = (z == 0) ? bq : (z == 1) ? bk : bv;
  const int tid = threadIdx.x, lane = tid & 63, wv = tid >> 6;
  const int quad = lane >> 4, l15 = lane & 15;
  const int wr = wv >> 2, wc = wv & 3;
  if (z < 2) {
    f16* O = z ? k : q;
#pragma unroll
    for (int mf = 0; mf < 4; ++mf)
#pragma unroll
      for (int nf = 0; nf < 4; ++nf) {
        int n = bcol + wc * 64 + nf * 16 + l15;
        float bb = bias[n];
        size_t row0 = arow + wr * 64 + mf * 16 + quad * 4;
#pragma unroll
        for (int r = 0; r < 4; ++r)
          O[(row0 + r) * DIM + n] = (f16)(acc[mf][nf][r] + bb);
      }
  } else {
#pragma unroll
    for (int mf = 0; mf < 4; ++mf)
#pragma unroll
      for (int nf = 0; nf < 4; ++nf) {
        int n = bcol + wc * 64 + nf * 16 + l15;
        float bb = bias[n];
        int row0 = (int)arow + wr * 64 + mf * 16 + quad * 4;  // 4-aligned, no batch straddle
        int bb_i = row0 >> 11, t0 = row0 & 2047;
        f16x4 pk;
#pragma unroll
        for (int r = 0; r < 4; ++r) pk[r] = (f16)(acc[mf][nf][r] + bb);
        *(f16x4*)(vT + ((size_t)bb_i * DIM + n) * T_ + t0) = pk;
      }
  }
}

// E = exp((q k^T)/32) with causal mask, fp16; per-row sums -> lrow (fp32
// atomics). BK=32 core jobs: 128-row q-stripe qs x 256-col k-panel kp,
// kp <= qs/2 (others fully masked) -> 72 uniform jobs/batch, grid 576,
// 2 blocks/CU. Partial tile iff qs <= 2*kp+1.
__global__ __launch_bounds__(512, 4) void scores_kernel(
    const f16* __restrict__ q, const f16* __restrict__ k,
    f16* __restrict__ E, float* __restrict__ lrow) {
  __shared__ uint16_t smem[24576];               // 48 KB
  const int bid = blockIdx.x;
  const int b = bid & 7;
  const int jid = bid >> 3;                      // [0,72)
  int qs = 0, c = 0;
  while (c + (qs / 2 + 1) <= jid) { c += qs / 2 + 1; ++qs; }
  const int kp = jid - c;                        // [0, qs/2]

  f32x4 acc[4][4];
  {
    f32x4 zz = {0.f, 0.f, 0.f, 0.f};
#pragma unroll
    for (int i = 0; i < 4; ++i)
#pragma unroll
      for (int j = 0; j < 4; ++j) acc[i][j] = zz;
  }
  gemm128x256_bk32((const uint16_t*)(q + ((size_t)b * T_ + qs * 128) * DIM),
                   (const uint16_t*)(k + ((size_t)b * T_ + kp * 256) * DIM),
                   DIM, DIM, 32, smem, acc);

  const int tid = threadIdx.x, lane = tid & 63, wv = tid >> 6;
  const int quad = lane >> 4, l15 = lane & 15;
  const int wr = wv >> 2, wc = wv & 3;
  f16*   Eb = E + (size_t)b * T_ * T_;
  float* lb = lrow + (size_t)b * T_;
  const bool diag = (qs <= 2 * kp + 1);
#pragma unroll
  for (int mf = 0; mf < 4; ++mf) {
    float rs[4] = {0.f, 0.f, 0.f, 0.f};
#pragma unroll
    for (int nf = 0; nf < 4; ++nf)
#pragma unroll
      for (int r = 0; r < 4; ++r) {
        int t = qs * 128 + wr * 64 + mf * 16 + quad * 4 + r;
        int s = kp * 256 + wc * 64 + nf * 16 + l15;
        float e = 0.f;
        if (!diag || s <= t) e = __expf(fminf(acc[mf][nf][r] * 0.03125f, 11.f));
        Eb[(size_t)t * T_ + s] = (f16)e;
        rs[r] += e;
      }
#pragma unroll
    for (int off = 1; off < 16; off <<= 1)
#pragma unroll
      for (int r = 0; r < 4; ++r) rs[r] += __shfl_xor(rs[r], off, 64);
    if (l15 == 0)
#pragma unroll
      for (int r = 0; r < 4; ++r)
        atomicAdd(&lb[qs * 128 + wr * 64 + mf * 16 + quad * 4 + r], rs[r]);
  }
}

// out = (E @ v) * invZ, fp32. 256 wgs, XCD b == batch b. Block = (b, nt128,
// pair): qi=pair AND qi=7-pair -> uniform 18 half-width iterations.
__global__ __launch_bounds__(512, 2) void pv_kernel(
    const f16* __restrict__ E, const f16* __restrict__ vT,
    const float* __restrict__ invZ, float* __restrict__ out) {
  __shared__ uint16_t smem[49152];               // 96 KB
  const int bid = blockIdx.x;
  const int b = bid & 7, local = bid >> 3;       // local in [0,32)
  const int nt = local & 7, pair = local >> 3;   // nt: 128-col tile, pair in [0,4)

  const float iz = invZ[b];
  const int tid = threadIdx.x, lane = tid & 63, wv = tid >> 6;
  const int quad = lane >> 4, l15 = lane & 15;
  const int wr = wv >> 2, wc = wv & 3;
  float* ob = out + (size_t)b * T_ * DIM;
  const uint16_t* Bv = (const uint16_t*)(vT + ((size_t)b * DIM + nt * 128) * (size_t)T_);

#pragma unroll 1
  for (int j = 0; j < 2; ++j) {
    const int qi = j ? (7 - pair) : pair;
    f32x4 acc[8][2];
    {
      f32x4 z = {0.f, 0.f, 0.f, 0.f};
#pragma unroll
      for (int i = 0; i < 8; ++i) { acc[i][0] = z; acc[i][1] = z; }
    }
    gemm256n128_8ph((const uint16_t*)(E + ((size_t)b * T_ + qi * 256) * (size_t)T_),
                    Bv, T_, T_, (qi + 1) * 2, smem, acc);
#pragma unroll
    for (int mf = 0; mf < 8; ++mf)
#pragma unroll
      for (int nf = 0; nf < 2; ++nf)
#pragma unroll
        for (int r = 0; r < 4; ++r) {
          int t = qi * 256 + wr * 128 + mf * 16 + quad * 4 + r;
          int n = nt * 128 + wc * 32 + nf * 16 + l15;
          ob[(size_t)t * DIM + n] = acc[mf][nf][r] * iz;
        }
  }
}

// ---------------- launch ----------------

extern "C" void kernel_launch(void* const* d_in, const int* in_sizes, int n_in,
                              void* d_out, int out_size, void* d_ws, size_t ws_size,
                              hipStream_t stream) {
  const float* x  = (const float*)d_in[0];
  const float* Wq = (const float*)d_in[1];
  const float* bq = (const float*)d_in[2];
  const float* Wk = (const float*)d_in[3];
  const float* bk = (const float*)d_in[4];
  const float* Wv = (const float*)d_in[5];
  const float* bv = (const float*)d_in[6];
  float* out = (float*)d_out;

  char* ws = (char*)d_ws;
  // layout (bytes):
  f16*   E    = (f16*)ws;                     //  0 .. 67,108,864 (B*T*T fp16)
  f16*   xf   = (f16*)ws;                     //  alias: xf lives in E[0..SZ), dead before scores
  f16*   q    = (f16*)(ws + 67108864);        //  33,554,432
  f16*   k    = (f16*)(ws + 100663296);       //  33,554,432
  f16*   vT   = (f16*)(ws + 134217728);       //  33,554,432
  f16*   WT   = (f16*)(ws + 167772160);       //  6,291,456
  float* lrow = (float*)(ws + 174063616);     //  65,536
  float* invZ = (float*)(ws + 174129152);     //  32
  if (ws_size < (size_t)174129184) return;    // fail cleanly, not with a GPU fault

  zero_lrow_kernel<<<64, 256, 0, stream>>>(lrow);
  conv_x_kernel<<<16384, 256, 0, stream>>>(x, xf);
  convT_w_kernel<<<dim3(16, 16, 3), 256, 0, stream>>>(Wq, Wk, Wv, WT);
  proj_kernel<<<dim3(1536), 512, 0, stream>>>(xf, WT, bq, bk, bv, q, k, vT);
  scores_kernel<<<dim3(576), 512, 0, stream>>>(q, k, E, lrow);
  reduce_z_kernel<<<B_, 256, 0, stream>>>(lrow, invZ);
  pv_kernel<<<dim3(256), 512, 0, stream>>>(E, vT, invZ, out);
}

// Round 6
// 354.094 us; speedup vs baseline: 1.0344x; 1.0225x over previous
//
#include <hip/hip_runtime.h>
#include <stdint.h>

// Causal self-attention, B=8 T=2048 D=EMB=1024, fp32 in/out.
// Pipeline: x,W -> fp16; q/k/v proj (f16 MFMA); S=qk^T/32; E=exp(S) fp16
// (scores ~N(0,1), max ~5.5 -> no overflow; reference softmax is GLOBAL per
// batch so no max-shift); Z_b = sum(E); out = (E@v)/Z fp32.
//
// R6: single-barrier-per-K-tile core for proj+scores. Evidence: occupancy
// (R4/R5) and bank conflicts (R5) both proven non-critical at flat 38%
// MfmaUtil -> the 2-barriers-per-8-MFMA lockstep is the limiter. New core:
// 256x256 tile, BK=32, 3-buffer LDS (96KB), per tile {stage(t+2); 12
// ds_reads; 32 MFMA/wave; barrier; vmcnt(4)} -> 1 barrier per 32 MFMA.
// WAR safety: reads of buf[(t+2)%3] completed (lgkm before MFMA_{t-1})
// before the end-of-(t-1) barrier, which precedes stage(t+2) issue.
// pv unchanged (one structural experiment per round).

#define B_   8
#define T_   2048
#define DIM  1024

typedef _Float16 f16;
typedef f16   f16x8 __attribute__((ext_vector_type(8)));
typedef f16   f16x4 __attribute__((ext_vector_type(4)));
typedef float f32x4 __attribute__((ext_vector_type(4)));

typedef const __attribute__((address_space(1))) void gvoid_t;
typedef __attribute__((address_space(3))) void lvoid_t;

// ================= staging/frag helpers =================
// 64-col layout (BK=64 pv core): 16B segments XOR-swizzled by (row&7).
__device__ __forceinline__ void stage_half256(const uint16_t* __restrict__ g, int ld,
                                              uint16_t* s, int tid) {
#pragma unroll
  for (int j = 0; j < 2; ++j) {
    int r   = j * 64 + (tid >> 3);
    int seg = (tid & 7) ^ (r & 7);
    const uint16_t* gp = g + (size_t)r * ld + seg * 8;
    uint16_t* sp = s + j * 4096 + (tid >> 6) * 512;  // wave-uniform; HW adds lane*16B
    __builtin_amdgcn_global_load_lds((gvoid_t*)gp, (lvoid_t*)sp, 16, 0, 0);
  }
}

__device__ __forceinline__ f16x8 frag64(const uint16_t* s, int r, int gseg) {
  return *(const f16x8*)(s + r * 64 + ((gseg ^ (r & 7)) * 8));
}

// 32-col layout: 4 segs/row, XOR by ((r>>1)&3) -> 16 lanes cover all 8
// bank-groups, 2 lanes each = conflict-free (verified R5: counter 0).
// One stage unit = 512 thr x 16B = 128 rows x 32 cols.
__device__ __forceinline__ void stage_u8k(const uint16_t* __restrict__ g, int ld,
                                          uint16_t* s, int tid) {
  int r   = tid >> 2;
  int seg = (tid & 3) ^ ((r >> 1) & 3);
  const uint16_t* gp = g + (size_t)r * ld + seg * 8;
  uint16_t* sp = s + (tid >> 6) * 512;
  __builtin_amdgcn_global_load_lds((gvoid_t*)gp, (lvoid_t*)sp, 16, 0, 0);
}

__device__ __forceinline__ f16x8 frag32(const uint16_t* s, int r, int gseg) {
  return *(const f16x8*)(s + r * 32 + ((gseg ^ ((r >> 1) & 3)) * 8));
}

__device__ __forceinline__ void lda4(const uint16_t* s, int rbase, int quad, int l15,
                                     f16x8 o[4][2]) {
#pragma unroll
  for (int mf = 0; mf < 4; ++mf) {
    int r = rbase + mf * 16 + l15;
#pragma unroll
    for (int kk = 0; kk < 2; ++kk) o[mf][kk] = frag64(s, r, kk * 4 + quad);
  }
}

__device__ __forceinline__ void ldb1(const uint16_t* s, int rbase, int quad, int l15,
                                     f16x8 o[2]) {
  int r = rbase + l15;
#pragma unroll
  for (int kk = 0; kk < 2; ++kk) o[kk] = frag64(s, r, kk * 4 + quad);
}

template <int M0, int N0>
__device__ __forceinline__ void mm8(f16x8 a[4][2], f16x8 b[2], f32x4 (&acc)[8][2]) {
#pragma unroll
  for (int kk = 0; kk < 2; ++kk)
#pragma unroll
    for (int mf = 0; mf < 4; ++mf)
      acc[M0 + mf][N0] = __builtin_amdgcn_mfma_f32_16x16x32_f16(
          a[mf][kk], b[kk], acc[M0 + mf][N0], 0, 0, 0);
}

#define SYNC_MFMA8(AA, BB, M0, N0)                     \
  __builtin_amdgcn_s_barrier();                        \
  asm volatile("s_waitcnt lgkmcnt(0)" ::: "memory");   \
  __builtin_amdgcn_s_setprio(1);                       \
  mm8<M0, N0>(AA, BB, acc);                            \
  __builtin_amdgcn_s_setprio(0);                       \
  __builtin_amdgcn_s_barrier();

// ---- R6 core: acc += A(256xK) @ B(256xK)^T, K = nTiles*32, nTiles >= 3 ----
// 512 thr = 8 waves 2Mx4N, per-wave 128x64, acc[8][4].
// LDS 96KB: A[3][256][32] + B[3][256][32] f16, rotating 3-buffer.
// Per tile: ONE barrier, counted vmcnt(4). Ledger: entry of tile t has
// {stage(t+1)}=4 loads in flight; issue stage(t+2) -> 8; end-of-tile
// vmcnt(4) retires stage(t+1). Stage flight time = 2 tiles.
__device__ __forceinline__ void gemm256_1bar(const uint16_t* __restrict__ gA,
                                             const uint16_t* __restrict__ gB,
                                             int lda, int ldb, int nTiles,
                                             uint16_t* smem, f32x4 (&acc)[8][4]) {
  const int tid = threadIdx.x, lane = tid & 63;
  const int quad = lane >> 4, l15 = lane & 15;
  const int wv = tid >> 6, wr = wv >> 2, wc = wv & 3;

#define STAGE_T(tt)                                                      \
  { uint16_t* sa = smem + ((tt) % 3) * 8192;                             \
    uint16_t* sb = smem + 24576 + ((tt) % 3) * 8192;                     \
    const uint16_t* ga = gA + (tt) * 32;                                 \
    const uint16_t* gb = gB + (tt) * 32;                                 \
    stage_u8k(ga,                     lda, sa,        tid);              \
    stage_u8k(ga + 128 * (size_t)lda, lda, sa + 4096, tid);              \
    stage_u8k(gb,                     ldb, sb,        tid);              \
    stage_u8k(gb + 128 * (size_t)ldb, ldb, sb + 4096, tid); }

#define READS_T(tt)                                                      \
  { const uint16_t* sa = smem + ((tt) % 3) * 8192;                       \
    const uint16_t* sb = smem + 24576 + ((tt) % 3) * 8192;               \
    _Pragma("unroll")                                                    \
    for (int mf = 0; mf < 8; ++mf)                                       \
      a[mf] = frag32(sa, wr * 128 + mf * 16 + l15, quad);                \
    _Pragma("unroll")                                                    \
    for (int nf = 0; nf < 4; ++nf)                                       \
      b[nf] = frag32(sb, wc * 64 + nf * 16 + l15, quad); }

#define MFMA_T                                                           \
  __builtin_amdgcn_s_setprio(1);                                         \
  _Pragma("unroll")                                                      \
  for (int mf = 0; mf < 8; ++mf)                                         \
    _Pragma("unroll")                                                    \
    for (int nf = 0; nf < 4; ++nf)                                       \
      acc[mf][nf] = __builtin_amdgcn_mfma_f32_16x16x32_f16(              \
          a[mf], b[nf], acc[mf][nf], 0, 0, 0);                           \
  __builtin_amdgcn_s_setprio(0);

  // prologue: stage(0), stage(1); retire stage(0), keep stage(1) in flight.
  STAGE_T(0)
  STAGE_T(1)
  asm volatile("s_waitcnt vmcnt(4)" ::: "memory");
  __builtin_amdgcn_s_barrier();

  f16x8 a[8], b[4];
#pragma unroll 1
  for (int t = 0; t < nTiles - 2; ++t) {
    STAGE_T(t + 2)                 // issue early: 2-tile flight time
    READS_T(t)                     // 12 ds_read_b128; compiler auto-lgkm
    MFMA_T                         // 32 MFMA/wave
    __builtin_amdgcn_s_barrier();  // all waves' reads of buf t complete
    asm volatile("s_waitcnt vmcnt(4)" ::: "memory");  // retire stage(t+1)
  }
  // t = nTiles-2: no stage; after barrier drain the last stage.
  READS_T(nTiles - 2)
  MFMA_T
  __builtin_amdgcn_s_barrier();
  asm volatile("s_waitcnt vmcnt(0)" ::: "memory");
  // t = nTiles-1: pure compute.
  READS_T(nTiles - 1)
  MFMA_T
#undef STAGE_T
#undef READS_T
#undef MFMA_T
}

// ---- NF=1 BK=64 core (pv, unchanged): acc += A(256xK) @ B(128xK)^T ----
__device__ __forceinline__ void gemm256n128_8ph(const uint16_t* __restrict__ gA,
                                                const uint16_t* __restrict__ gB,
                                                int lda, int ldb, int nIter,
                                                uint16_t* smem, f32x4 (&acc)[8][2]) {
  const int tid = threadIdx.x, lane = tid & 63;
  const int quad = lane >> 4, l15 = lane & 15;
  const int wv = tid >> 6, wr = wv >> 2, wc = wv & 3;

  uint16_t* sA0 = smem;
  uint16_t* sA1 = smem + 16384;
  uint16_t* sB0 = smem + 32768;
  uint16_t* sB1 = smem + 40960;

  stage_half256(gA,                     lda, sA0,        tid);
  stage_half256(gA + 128 * (size_t)lda, lda, sA0 + 8192, tid);
  stage_half256(gB,                     ldb, sB0,        tid);
  stage_half256(gB + 64,                ldb, sB1,        tid);
  asm volatile("s_waitcnt vmcnt(2)" ::: "memory");
  __builtin_amdgcn_s_barrier();

  f16x8 alo[4][2], ahi[4][2], b0[2], b1[2];
#pragma unroll 1
  for (int it = 0; it < nIter - 1; ++it) {
    const int t1 = 2 * it + 1, t2 = 2 * it + 2, t3 = 2 * it + 3;
    const uint16_t* gA1 = gA + t1 * 64;
    const uint16_t* gA2 = gA + t2 * 64;

    lda4(sA0, wr * 128,      quad, l15, alo);
    ldb1(sB0, wc * 32,       quad, l15, b0);
    stage_half256(gA1, lda, sA1, tid);
    SYNC_MFMA8(alo, b0, 0, 0)
    ldb1(sB0, wc * 32 + 16,  quad, l15, b1);
    stage_half256(gA1 + 128 * (size_t)lda, lda, sA1 + 8192, tid);
    SYNC_MFMA8(alo, b1, 0, 1)
    lda4(sA0, wr * 128 + 64, quad, l15, ahi);
    stage_half256(gB + t2 * 64, ldb, sB0, tid);
    SYNC_MFMA8(ahi, b1, 4, 1)
    asm volatile("s_waitcnt vmcnt(2)" ::: "memory");
    SYNC_MFMA8(ahi, b0, 4, 0)
    lda4(sA1, wr * 128,      quad, l15, alo);
    ldb1(sB1, wc * 32,       quad, l15, b0);
    stage_half256(gA2, lda, sA0, tid);
    SYNC_MFMA8(alo, b0, 0, 0)
    ldb1(sB1, wc * 32 + 16,  quad, l15, b1);
    stage_half256(gA2 + 128 * (size_t)lda, lda, sA0 + 8192, tid);
    SYNC_MFMA8(alo, b1, 0, 1)
    lda4(sA1, wr * 128 + 64, quad, l15, ahi);
    stage_half256(gB + t3 * 64, ldb, sB1, tid);
    SYNC_MFMA8(ahi, b1, 4, 1)
    asm volatile("s_waitcnt vmcnt(2)" ::: "memory");
    SYNC_MFMA8(ahi, b0, 4, 0)
  }
  {
    const uint16_t* gA1 = gA + (2 * nIter - 1) * 64;
    lda4(sA0, wr * 128,      quad, l15, alo);
    ldb1(sB0, wc * 32,       quad, l15, b0);
    stage_half256(gA1, lda, sA1, tid);
    SYNC_MFMA8(alo, b0, 0, 0)
    ldb1(sB0, wc * 32 + 16,  quad, l15, b1);
    stage_half256(gA1 + 128 * (size_t)lda, lda, sA1 + 8192, tid);
    SYNC_MFMA8(alo, b1, 0, 1)
    lda4(sA0, wr * 128 + 64, quad, l15, ahi);
    SYNC_MFMA8(ahi, b1, 4, 1)
    asm volatile("s_waitcnt vmcnt(0)" ::: "memory");
    SYNC_MFMA8(ahi, b0, 4, 0)
    lda4(sA1, wr * 128,      quad, l15, alo);
    ldb1(sB1, wc * 32,       quad, l15, b0);
    SYNC_MFMA8(alo, b0, 0, 0)
    ldb1(sB1, wc * 32 + 16,  quad, l15, b1);
    SYNC_MFMA8(alo, b1, 0, 1)
    lda4(sA1, wr * 128 + 64, quad, l15, ahi);
    SYNC_MFMA8(ahi, b1, 4, 1)
    SYNC_MFMA8(ahi, b0, 4, 0)
  }
}

__device__ __forceinline__ void zero_acc8(f32x4 (&acc)[8][4]) {
  f32x4 z = {0.f, 0.f, 0.f, 0.f};
#pragma unroll
  for (int i = 0; i < 8; ++i)
#pragma unroll
    for (int j = 0; j < 4; ++j) acc[i][j] = z;
}

// ---------------- helpers ----------------

__global__ void zero_lrow_kernel(float* __restrict__ lrow) {
  lrow[blockIdx.x * 256 + threadIdx.x] = 0.f;
}

__global__ void conv_x_kernel(const float* __restrict__ x, f16* __restrict__ xf) {
  size_t i = (size_t)blockIdx.x * 256 + threadIdx.x;
  float4 v = ((const float4*)x)[i];
  f16x4 o = {(f16)v.x, (f16)v.y, (f16)v.z, (f16)v.w};
  ((f16x4*)xf)[i] = o;
}

// W [K][N] fp32 -> WT fp16 [z][N][K]
__global__ void convT_w_kernel(const float* __restrict__ Wq, const float* __restrict__ Wk,
                               const float* __restrict__ Wv, f16* __restrict__ WT) {
  __shared__ float tile[64][65];
  const int z = blockIdx.z;
  const float* W = (z == 0) ? Wq : (z == 1) ? Wk : Wv;
  const int r0 = blockIdx.x * 64, c0 = blockIdx.y * 64, tid = threadIdx.x;
#pragma unroll
  for (int i = 0; i < 16; ++i) {
    int rr = (tid >> 6) + 4 * i, cc = tid & 63;
    tile[rr][cc] = W[(size_t)(r0 + rr) * DIM + c0 + cc];
  }
  __syncthreads();
#pragma unroll
  for (int i = 0; i < 16; ++i) {
    int nn = (tid >> 6) + 4 * i, kk = tid & 63;
    WT[(size_t)z * DIM * DIM + (size_t)(c0 + nn) * DIM + r0 + kk] = (f16)tile[kk][nn];
  }
}

__global__ void reduce_z_kernel(const float* __restrict__ lrow, float* __restrict__ invZ) {
  const int b = blockIdx.x, tid = threadIdx.x;
  float s = 0.f;
  for (int i = tid; i < T_; i += 256) s += lrow[(size_t)b * T_ + i];
#pragma unroll
  for (int off = 1; off < 64; off <<= 1) s += __shfl_xor(s, off, 64);
  __shared__ float red[4];
  if ((tid & 63) == 0) red[tid >> 6] = s;
  __syncthreads();
  if (tid == 0) invZ[b] = 1.0f / (red[0] + red[1] + red[2] + red[3]);
}

// ---------------- main kernels ----------------

// [16384,1024] x [1024,1024]^T + bias, 256x256 tiles, R6 1-barrier core.
// Job order: XCD x owns A panels bx in [8x,8x+8), cycles 12 (z,by) combos.
__global__ __launch_bounds__(512, 2) void proj_kernel(
    const f16* __restrict__ xf, const f16* __restrict__ WT,
    const float* __restrict__ bq, const float* __restrict__ bk, const float* __restrict__ bv,
    f16* __restrict__ q, f16* __restrict__ k, f16* __restrict__ vT) {
  __shared__ uint16_t smem[49152];  // 96 KB

  const int bid = blockIdx.x;
  const int xcd = bid & 7, local = bid >> 3;     // local in [0,96)
  const int bx = xcd * 8 + (local & 7);
  const int zy = local >> 3;                     // 0..11
  const int z = zy >> 2, by = zy & 3;
  const size_t arow = (size_t)bx * 256;
  const int    bcol = by * 256;

  f32x4 acc[8][4];
  zero_acc8(acc);
  gemm256_1bar((const uint16_t*)xf + arow * DIM,
               (const uint16_t*)WT + (size_t)z * DIM * DIM + (size_t)bcol * DIM,
               DIM, DIM, 32, smem, acc);

  const float* bias = (z == 0) ? bq : (z == 1) ? bk : bv;
  const int tid = threadIdx.x, lane = tid & 63, wv = tid >> 6;
  const int quad = lane >> 4, l15 = lane & 15;
  const int wr = wv >> 2, wc = wv & 3;
  if (z < 2) {
    f16* O = z ? k : q;
#pragma unroll
    for (int mf = 0; mf < 8; ++mf)
#pragma unroll
      for (int nf = 0; nf < 4; ++nf) {
        int n = bcol + wc * 64 + nf * 16 + l15;
        float bb = bias[n];
        size_t row0 = arow + wr * 128 + mf * 16 + quad * 4;
#pragma unroll
        for (int r = 0; r < 4; ++r)
          O[(row0 + r) * DIM + n] = (f16)(acc[mf][nf][r] + bb);
      }
  } else {
#pragma unroll
    for (int mf = 0; mf < 8; ++mf)
#pragma unroll
      for (int nf = 0; nf < 4; ++nf) {
        int n = bcol + wc * 64 + nf * 16 + l15;
        float bb = bias[n];
        int row0 = (int)arow + wr * 128 + mf * 16 + quad * 4;  // 4-aligned, no batch straddle
        int bb_i = row0 >> 11, t0 = row0 & 2047;
        f16x4 pk;
#pragma unroll
        for (int r = 0; r < 4; ++r) pk[r] = (f16)(acc[mf][nf][r] + bb);
        *(f16x4*)(vT + ((size_t)bb_i * DIM + n) * T_ + t0) = pk;
      }
  }
}

// E = exp((q k^T)/32) with causal mask, fp16; per-row sums -> lrow (fp32
// atomics). 256^2 tiles: 36 causal tiles/batch, XCD b == batch b (288 wgs).
__global__ __launch_bounds__(512, 2) void scores_kernel(
    const f16* __restrict__ q, const f16* __restrict__ k,
    f16* __restrict__ E, float* __restrict__ lrow) {
  __shared__ uint16_t smem[49152];
  const int bid = blockIdx.x;
  const int b = bid & 7, tri = bid >> 3;         // tri in [0,36)
  int qi = 0;
  while ((qi + 1) * (qi + 2) / 2 <= tri) ++qi;   // qi in [0,8)
  const int ki = tri - qi * (qi + 1) / 2;

  f32x4 acc[8][4];
  zero_acc8(acc);
  gemm256_1bar((const uint16_t*)(q + ((size_t)b * T_ + qi * 256) * DIM),
               (const uint16_t*)(k + ((size_t)b * T_ + ki * 256) * DIM),
               DIM, DIM, 32, smem, acc);

  const int tid = threadIdx.x, lane = tid & 63, wv = tid >> 6;
  const int quad = lane >> 4, l15 = lane & 15;
  const int wr = wv >> 2, wc = wv & 3;
  f16*   Eb = E + (size_t)b * T_ * T_;
  float* lb = lrow + (size_t)b * T_;
  const bool diag = (ki == qi);
#pragma unroll
  for (int mf = 0; mf < 8; ++mf) {
    float rs[4] = {0.f, 0.f, 0.f, 0.f};
#pragma unroll
    for (int nf = 0; nf < 4; ++nf)
#pragma unroll
      for (int r = 0; r < 4; ++r) {
        int t = qi * 256 + wr * 128 + mf * 16 + quad * 4 + r;
        int s = ki * 256 + wc * 64 + nf * 16 + l15;
        float e = 0.f;
        if (!diag || s <= t) e = __expf(fminf(acc[mf][nf][r] * 0.03125f, 11.f));
        Eb[(size_t)t * T_ + s] = (f16)e;
        rs[r] += e;
      }
#pragma unroll
    for (int off = 1; off < 16; off <<= 1)
#pragma unroll
      for (int r = 0; r < 4; ++r) rs[r] += __shfl_xor(rs[r], off, 64);
    if (l15 == 0)
#pragma unroll
      for (int r = 0; r < 4; ++r)
        atomicAdd(&lb[qi * 256 + wr * 128 + mf * 16 + quad * 4 + r], rs[r]);
  }
}

// out = (E @ v) * invZ, fp32. 256 wgs, XCD b == batch b. Block = (b, nt128,
// pair): qi=pair AND qi=7-pair -> uniform 18 half-width iterations.
__global__ __launch_bounds__(512, 2) void pv_kernel(
    const f16* __restrict__ E, const f16* __restrict__ vT,
    const float* __restrict__ invZ, float* __restrict__ out) {
  __shared__ uint16_t smem[49152];               // 96 KB
  const int bid = blockIdx.x;
  const int b = bid & 7, local = bid >> 3;       // local in [0,32)
  const int nt = local & 7, pair = local >> 3;   // nt: 128-col tile, pair in [0,4)

  const float iz = invZ[b];
  const int tid = threadIdx.x, lane = tid & 63, wv = tid >> 6;
  const int quad = lane >> 4, l15 = lane & 15;
  const int wr = wv >> 2, wc = wv & 3;
  float* ob = out + (size_t)b * T_ * DIM;
  const uint16_t* Bv = (const uint16_t*)(vT + ((size_t)b * DIM + nt * 128) * (size_t)T_);

#pragma unroll 1
  for (int j = 0; j < 2; ++j) {
    const int qi = j ? (7 - pair) : pair;
    f32x4 acc[8][2];
    {
      f32x4 z = {0.f, 0.f, 0.f, 0.f};
#pragma unroll
      for (int i = 0; i < 8; ++i) { acc[i][0] = z; acc[i][1] = z; }
    }
    gemm256n128_8ph((const uint16_t*)(E + ((size_t)b * T_ + qi * 256) * (size_t)T_),
                    Bv, T_, T_, (qi + 1) * 2, smem, acc);
#pragma unroll
    for (int mf = 0; mf < 8; ++mf)
#pragma unroll
      for (int nf = 0; nf < 2; ++nf)
#pragma unroll
        for (int r = 0; r < 4; ++r) {
          int t = qi * 256 + wr * 128 + mf * 16 + quad * 4 + r;
          int n = nt * 128 + wc * 32 + nf * 16 + l15;
          ob[(size_t)t * DIM + n] = acc[mf][nf][r] * iz;
        }
  }
}

// ---------------- launch ----------------

extern "C" void kernel_launch(void* const* d_in, const int* in_sizes, int n_in,
                              void* d_out, int out_size, void* d_ws, size_t ws_size,
                              hipStream_t stream) {
  const float* x  = (const float*)d_in[0];
  const float* Wq = (const float*)d_in[1];
  const float* bq = (const float*)d_in[2];
  const float* Wk = (const float*)d_in[3];
  const float* bk = (const float*)d_in[4];
  const float* Wv = (const float*)d_in[5];
  const float* bv = (const float*)d_in[6];
  float* out = (float*)d_out;

  char* ws = (char*)d_ws;
  // layout (bytes):
  f16*   E    = (f16*)ws;                     //  0 .. 67,108,864 (B*T*T fp16)
  f16*   xf   = (f16*)ws;                     //  alias: xf lives in E[0..SZ), dead before scores
  f16*   q    = (f16*)(ws + 67108864);        //  33,554,432
  f16*   k    = (f16*)(ws + 100663296);       //  33,554,432
  f16*   vT   = (f16*)(ws + 134217728);       //  33,554,432
  f16*   WT   = (f16*)(ws + 167772160);       //  6,291,456
  float* lrow = (float*)(ws + 174063616);     //  65,536
  float* invZ = (float*)(ws + 174129152);     //  32
  if (ws_size < (size_t)174129184) return;    // fail cleanly, not with a GPU fault

  zero_lrow_kernel<<<64, 256, 0, stream>>>(lrow);
  conv_x_kernel<<<16384, 256, 0, stream>>>(x, xf);
  convT_w_kernel<<<dim3(16, 16, 3), 256, 0, stream>>>(Wq, Wk, Wv, WT);
  proj_kernel<<<dim3(768), 512, 0, stream>>>(xf, WT, bq, bk, bv, q, k, vT);
  scores_kernel<<<dim3(288), 512, 0, stream>>>(q, k, E, lrow);
  reduce_z_kernel<<<B_, 256, 0, stream>>>(lrow, invZ);
  pv_kernel<<<dim3(256), 512, 0, stream>>>(E, vT, invZ, out);
}